// Round 6
// baseline (3325.297 us; speedup 1.0000x reference)
//
#include <hip/hip_runtime.h>

typedef __attribute__((ext_vector_type(8))) __bf16 bf16x8;
typedef __attribute__((ext_vector_type(4))) float f32x4;

#define DEV __device__ __forceinline__

DEV unsigned short f2bf(float f) {
  unsigned int u = __float_as_uint(f);
  u += 0x7FFFu + ((u >> 16) & 1u);   // RNE
  return (unsigned short)(u >> 16);
}

// Perf-only global barrier: monotonic counter, device scope, capped spin.
// Early bail NEVER affects correctness (barrier only aligns K-windows).
DEV void gbar(int* cnt, int target) {
  __syncthreads();
  if (threadIdx.x == 0) {
    __hip_atomic_fetch_add(cnt, 1, __ATOMIC_RELAXED, __HIP_MEMORY_SCOPE_AGENT);
    int it = 0;
    while (__hip_atomic_load(cnt, __ATOMIC_RELAXED, __HIP_MEMORY_SCOPE_AGENT) < target &&
           ++it < (1 << 18))
      __builtin_amdgcn_s_sleep(8);
  }
  __syncthreads();
}

// ---------------- kernel 1: f32 -> bf16 (vectorized) ----------------
__global__ __launch_bounds__(256) void k_f32_to_bf16(const float* __restrict__ x,
                                                     unsigned short* __restrict__ y) {
  size_t i = ((size_t)blockIdx.x * 256 + threadIdx.x) * 8;
  float4 a = *(const float4*)(x + i);
  float4 b = *(const float4*)(x + i + 4);
  union { unsigned short u[8]; uint4 v; } o;
  o.u[0] = f2bf(a.x); o.u[1] = f2bf(a.y); o.u[2] = f2bf(a.z); o.u[3] = f2bf(a.w);
  o.u[4] = f2bf(b.x); o.u[5] = f2bf(b.y); o.u[6] = f2bf(b.z); o.u[7] = f2bf(b.w);
  *(uint4*)(y + i) = o.v;
}

// ------- kernel 2: AWQ int4 dequant -> W^T bf16 [N][K] (LDS transpose) -------
__global__ __launch_bounds__(256) void k_dequant_t(const int* __restrict__ qw,
                                                   const int* __restrict__ qz,
                                                   const float* __restrict__ sc,
                                                   unsigned short* __restrict__ wt,
                                                   int K, int N) {
  __shared__ __align__(16) unsigned short st[64][72];
  const int k0 = blockIdx.x * 64, n0 = blockIdx.y * 64;
  const int t = threadIdx.x;
  const int g = k0 >> 7;
  const int Np = N >> 3;
#pragma unroll
  for (int it = 0; it < 2; ++it) {
    int idx = t + it * 256;
    int k = idx >> 3;
    int nc = idx & 7;
    unsigned int w = (unsigned int)qw[(size_t)(k0 + k) * Np + (n0 >> 3) + nc];
    unsigned int z = (unsigned int)qz[(size_t)g * Np + (n0 >> 3) + nc];
#pragma unroll
    for (int i = 0; i < 8; ++i) {
      float s = sc[(size_t)g * N + n0 + nc * 8 + i];
      float v = ((float)(int)((w >> (4 * i)) & 0xFu) -
                 (float)(int)((z >> (4 * i)) & 0xFu)) * s;
      st[nc * 8 + i][k] = f2bf(v);
    }
  }
  __syncthreads();
  const int n = t >> 2, c = t & 3;
  uint4 v0 = *(const uint4*)&st[n][c * 16];
  uint4 v1 = *(const uint4*)&st[n][c * 16 + 8];
  unsigned short* dst = wt + (size_t)(n0 + n) * K + k0 + c * 16;
  *(uint4*)dst = v0;
  *(uint4*)(dst + 8) = v1;
}

// ------- kernel 3: persistent lockstep 256x256 8-phase GEMM  C = A * B^T -------
// Grid = 256 blocks exactly (1/CU, all co-resident). Each block loops over
// output tiles in phases of 256 tiles:
//   GEMM2 (nbn=16): phase p: m = p*16+(idx&15), n = idx>>4  (A-split; all 16
//     readers of A panel m share XCD m%8 -> L2; B via L3)
//   GEMM1 (nbn=64): phase p: m = idx>>3, n = p*8+(idx&7)    (B-panel readers
//     share one XCD; A 64MiB stays L3-resident across phases)
// Soft global barrier every 32 K-tiles + phase ends bounds drift so the live
// K-window (~64MiB) fits L3 (R5 post-mortem: unbounded drift + multi-wave
// dispatch chaos defeated every raster; FETCH stayed ~8x compulsory).
// C-stores non-temporal (write streams must not evict A/B).

#define STAGE_A(h) do { const unsigned short* g_ = A + gsA + (size_t)(h) * 32;               \
  __builtin_amdgcn_global_load_lds((const __attribute__((address_space(1))) void*)g_,        \
      (__attribute__((address_space(3))) void*)(&sA[(h) & 3][0] + tid * 8), 16, 0, 0);       \
  __builtin_amdgcn_global_load_lds((const __attribute__((address_space(1))) void*)(g_ + (size_t)128 * K), \
      (__attribute__((address_space(3))) void*)(&sA[(h) & 3][4096] + tid * 8), 16, 0, 0); } while (0)
#define STAGE_B(h) do { const unsigned short* g_ = B + gsB + (size_t)(h) * 32;               \
  __builtin_amdgcn_global_load_lds((const __attribute__((address_space(1))) void*)g_,        \
      (__attribute__((address_space(3))) void*)(&sB[(h) & 3][0] + tid * 8), 16, 0, 0);       \
  __builtin_amdgcn_global_load_lds((const __attribute__((address_space(1))) void*)(g_ + (size_t)128 * K), \
      (__attribute__((address_space(3))) void*)(&sB[(h) & 3][4096] + tid * 8), 16, 0, 0); } while (0)

#define LDA(s, m) (*(const bf16x8*)((const char*)&sA[s][0] + offA + (m) * 1024))
#define LDB(s, n) (*(const bf16x8*)((const char*)&sB[s][0] + offB + (n) * 1024))

template <int GELU>
__global__ __launch_bounds__(512, 2) void k_gemm256(const unsigned short* __restrict__ A,
                                                    const unsigned short* __restrict__ B,
                                                    void* __restrict__ C,
                                                    int M, int N, int K,
                                                    int* __restrict__ bar) {
  __shared__ __align__(16) unsigned short sA[4][8192];
  __shared__ __align__(16) unsigned short sB[4][8192];
  const int tid = threadIdx.x;
  const int lane = tid & 63;
  const int wave = tid >> 6;
  const int wm = wave >> 2, wn = wave & 3;
  const int r16 = lane & 15, q = lane >> 4;
  const int idx = blockIdx.x;

  const int nbn = N >> 8;
  const int nph = ((M >> 8) * nbn) >> 8;
  const int NT = K >> 6;
  int round = 0;

  const int rA = wm * 128 + r16;
  const int rB = wn * 64 + r16;
  const int offA = rA * 64 + ((q * 16) ^ (((rA >> 1) & 3) << 4));
  const int offB = rB * 64 + ((q * 16) ^ (((rB >> 1) & 3) << 4));
  const int sr = tid >> 2;                        // staging row (0..127)
  const int ssrc = (tid & 3) ^ ((sr >> 1) & 3);   // pre-swizzled global 16B slot

  for (int p = 0; p < nph; ++p) {
    int m_t, n_t;
    if (nbn == 16) { m_t = p * 16 + (idx & 15); n_t = idx >> 4; }
    else           { m_t = idx >> 3;            n_t = p * 8 + (idx & 7); }
    const int m0 = m_t * 256, n0 = n_t * 256;

    const size_t gsA = (size_t)(m0 + sr) * K + (size_t)ssrc * 8;
    const size_t gsB = (size_t)(n0 + sr) * K + (size_t)ssrc * 8;

    f32x4 acc[8][4] = {};

    // prologue: slabs 0,1,2 (A+B); 0,1 resident, slab 2 in flight
    STAGE_A(0); STAGE_B(0); STAGE_A(1); STAGE_B(1); STAGE_A(2); STAGE_B(2);
    asm volatile("s_waitcnt vmcnt(4)" ::: "memory");
    __builtin_amdgcn_s_barrier();

    for (int t = 0; t < NT; ++t) {
      const int s0 = (2 * t) & 3, s1 = (2 * t + 1) & 3;
      const int h3 = 2 * t + 3, h4 = 2 * t + 4;
      bf16x8 af[4], bf[4];

      // ---- phase 1: kk0, m0-3 ; stage A(2t+3)
#pragma unroll
      for (int i = 0; i < 4; ++i) af[i] = LDA(s0, i);
#pragma unroll
      for (int j = 0; j < 4; ++j) bf[j] = LDB(s0, j);
      if (h3 < 2 * NT) STAGE_A(h3);
      __builtin_amdgcn_s_barrier();
      __builtin_amdgcn_s_setprio(1);
#pragma unroll
      for (int i = 0; i < 4; ++i)
#pragma unroll
        for (int j = 0; j < 4; ++j)
          acc[i][j] = __builtin_amdgcn_mfma_f32_16x16x32_bf16(af[i], bf[j], acc[i][j], 0, 0, 0);
      __builtin_amdgcn_s_setprio(0);
      __builtin_amdgcn_s_barrier();

      // ---- phase 2: kk0, m4-7 ; stage B(2t+3)
#pragma unroll
      for (int i = 0; i < 4; ++i) af[i] = LDA(s0, 4 + i);
      if (h3 < 2 * NT) STAGE_B(h3);
      __builtin_amdgcn_s_barrier();
      __builtin_amdgcn_s_setprio(1);
#pragma unroll
      for (int i = 0; i < 4; ++i)
#pragma unroll
        for (int j = 0; j < 4; ++j)
          acc[4 + i][j] = __builtin_amdgcn_mfma_f32_16x16x32_bf16(af[i], bf[j], acc[4 + i][j], 0, 0, 0);
      __builtin_amdgcn_s_setprio(0);
      __builtin_amdgcn_s_barrier();

      // ---- phase 3: kk1, m0-3 ; stage A(2t+4)
#pragma unroll
      for (int i = 0; i < 4; ++i) af[i] = LDA(s1, i);
#pragma unroll
      for (int j = 0; j < 4; ++j) bf[j] = LDB(s1, j);
      if (h4 < 2 * NT) STAGE_A(h4);
      __builtin_amdgcn_s_barrier();
      __builtin_amdgcn_s_setprio(1);
#pragma unroll
      for (int i = 0; i < 4; ++i)
#pragma unroll
        for (int j = 0; j < 4; ++j)
          acc[i][j] = __builtin_amdgcn_mfma_f32_16x16x32_bf16(af[i], bf[j], acc[i][j], 0, 0, 0);
      __builtin_amdgcn_s_setprio(0);
      __builtin_amdgcn_s_barrier();

      // ---- phase 4: kk1, m4-7 ; stage B(2t+4) ; boundary vmcnt
#pragma unroll
      for (int i = 0; i < 4; ++i) af[i] = LDA(s1, 4 + i);
      if (h4 < 2 * NT) STAGE_B(h4);
      __builtin_amdgcn_s_barrier();
      __builtin_amdgcn_s_setprio(1);
#pragma unroll
      for (int i = 0; i < 4; ++i)
#pragma unroll
        for (int j = 0; j < 4; ++j)
          acc[4 + i][j] = __builtin_amdgcn_mfma_f32_16x16x32_bf16(af[i], bf[j], acc[4 + i][j], 0, 0, 0);
      __builtin_amdgcn_s_setprio(0);
      if (t < NT - 2) { asm volatile("s_waitcnt vmcnt(4)" ::: "memory"); }
      else            { asm volatile("s_waitcnt vmcnt(0)" ::: "memory"); }
      __builtin_amdgcn_s_barrier();

      // lockstep: bound K-window drift to <=32 tiles
      if ((t & 31) == 31 && t + 1 < NT) gbar(bar, 256 * (++round));
    }

    // epilogue: C/D layout col=lane&15, row=(lane>>4)*4+reg ; NT stores
    const int mb = m0 + wm * 128 + q * 4;
    const int nb = n0 + wn * 64 + r16;
#pragma unroll
    for (int i = 0; i < 8; ++i) {
#pragma unroll
      for (int j = 0; j < 4; ++j) {
#pragma unroll
        for (int r = 0; r < 4; ++r) {
          int row = mb + i * 16 + r;
          int col = nb + j * 16;
          float v = acc[i][j][r];
          if (GELU) {
            v = 0.5f * v * (1.0f + erff(v * 0.70710678118654752440f));
            __builtin_nontemporal_store(f2bf(v),
                (unsigned short*)C + (size_t)row * N + col);
          } else {
            __builtin_nontemporal_store(v, (float*)C + (size_t)row * N + col);
          }
        }
      }
    }

    if (p + 1 < nph) gbar(bar, 256 * (++round));   // align phase starts
  }
}

extern "C" void kernel_launch(void* const* d_in, const int* in_sizes, int n_in,
                              void* d_out, int out_size, void* d_ws, size_t ws_size,
                              hipStream_t stream) {
  const float* x  = (const float*)d_in[0];
  const int* uqw  = (const int*)d_in[1];
  const int* uqz  = (const int*)d_in[2];
  const float* usc = (const float*)d_in[3];
  const int* dqw  = (const int*)d_in[4];
  const int* dqz  = (const int*)d_in[5];
  const float* dsc = (const float*)d_in[6];
  float* out = (float*)d_out;

  const int T = 8192, D = 4096, F = 16384;
  char* ws = (char*)d_ws;
  unsigned short* xb = (unsigned short*)ws;                                  // 64 MiB
  unsigned short* h  = (unsigned short*)(ws + (size_t)T * D * 2);            // 256 MiB
  unsigned short* wt = (unsigned short*)(ws + (size_t)T * D * 2 + (size_t)T * F * 2); // 128 MiB

  k_f32_to_bf16<<<dim3((T * D) / (256 * 8)), 256, 0, stream>>>(x, xb);
  k_dequant_t<<<dim3(D / 64, F / 64), 256, 0, stream>>>(uqw, uqz, usc, wt, D, F);

  // GEMM1 barrier counter lives in d_out (dead until GEMM2 writes it)
  hipMemsetAsync(d_out, 0, 8, stream);
  k_gemm256<1><<<dim3(256), 512, 0, stream>>>(xb, wt, (void*)h, T, F, D, (int*)d_out);

  k_dequant_t<<<dim3(F / 64, D / 64), 256, 0, stream>>>(dqw, dqz, dsc, wt, F, D);

  // GEMM2 barrier counter lives in xb (dead after GEMM1)
  hipMemsetAsync(xb, 0, 8, stream);
  k_gemm256<0><<<dim3(256), 512, 0, stream>>>(h, wt, (void*)out, T, D, F, (int*)xb);
}

// Round 7
// 2638.920 us; speedup vs baseline: 1.2601x; 1.2601x over previous
//
#include <hip/hip_runtime.h>

typedef __attribute__((ext_vector_type(8))) __bf16 bf16x8;
typedef __attribute__((ext_vector_type(4))) float f32x4;

#define DEV __device__ __forceinline__

DEV unsigned short f2bf(float f) {
  unsigned int u = __float_as_uint(f);
  u += 0x7FFFu + ((u >> 16) & 1u);   // RNE
  return (unsigned short)(u >> 16);
}

// ---------------- kernel 1: f32 -> bf16 (vectorized) ----------------
__global__ __launch_bounds__(256) void k_f32_to_bf16(const float* __restrict__ x,
                                                     unsigned short* __restrict__ y) {
  size_t i = ((size_t)blockIdx.x * 256 + threadIdx.x) * 8;
  float4 a = *(const float4*)(x + i);
  float4 b = *(const float4*)(x + i + 4);
  union { unsigned short u[8]; uint4 v; } o;
  o.u[0] = f2bf(a.x); o.u[1] = f2bf(a.y); o.u[2] = f2bf(a.z); o.u[3] = f2bf(a.w);
  o.u[4] = f2bf(b.x); o.u[5] = f2bf(b.y); o.u[6] = f2bf(b.z); o.u[7] = f2bf(b.w);
  *(uint4*)(y + i) = o.v;
}

// ------- kernel 2: AWQ int4 dequant -> W^T bf16 [N][K] (LDS transpose) -------
__global__ __launch_bounds__(256) void k_dequant_t(const int* __restrict__ qw,
                                                   const int* __restrict__ qz,
                                                   const float* __restrict__ sc,
                                                   unsigned short* __restrict__ wt,
                                                   int K, int N) {
  __shared__ __align__(16) unsigned short st[64][72];
  const int k0 = blockIdx.x * 64, n0 = blockIdx.y * 64;
  const int t = threadIdx.x;
  const int g = k0 >> 7;
  const int Np = N >> 3;
#pragma unroll
  for (int it = 0; it < 2; ++it) {
    int idx = t + it * 256;
    int k = idx >> 3;
    int nc = idx & 7;
    unsigned int w = (unsigned int)qw[(size_t)(k0 + k) * Np + (n0 >> 3) + nc];
    unsigned int z = (unsigned int)qz[(size_t)g * Np + (n0 >> 3) + nc];
#pragma unroll
    for (int i = 0; i < 8; ++i) {
      float s = sc[(size_t)g * N + n0 + nc * 8 + i];
      float v = ((float)(int)((w >> (4 * i)) & 0xFu) -
                 (float)(int)((z >> (4 * i)) & 0xFu)) * s;
      st[nc * 8 + i][k] = f2bf(v);
    }
  }
  __syncthreads();
  const int n = t >> 2, c = t & 3;
  uint4 v0 = *(const uint4*)&st[n][c * 16];
  uint4 v1 = *(const uint4*)&st[n][c * 16 + 8];
  unsigned short* dst = wt + (size_t)(n0 + n) * K + k0 + c * 16;
  *(uint4*)dst = v0;
  *(uint4*)(dst + 8) = v1;
}

// ---------------- kernel 3: 256x256 8-phase GEMM  C = A[M][K] * B^T([N][K]) ----
// 512 threads = 8 waves (2 M x 4 N), per-wave out 128x64 (acc[8][4] of 16x16).
// LDS: A,B rings of 4 K-slabs (256 rows x 32 k bf16 = 16KB each) = 128 KiB.
// R6 post-mortem: kernel is LATENCY-bound, not HBM-bound (dur invariant to
// FETCH 1.3-4.3GB; HBM only 2.7/6.3 TB/s; MfmaUtil pinned 34% = Little's-law
// limit of ~4 outstanding loads/wave). Fix: DEEP counted vmcnt -- two waits
// per K-tile of vmcnt(8) (2 slab-pairs in flight), each placed immediately
// before a barrier so every wave's DMA is ordered before any read (staging is
// cross-wave: a wave reads rows staged by other waves).
// Swizzle: 16B slot ^= (row>>1)&3 on both pre-swizzled source and ds_read
// (2 lanes/bank => free). Raster: R3's grouped-m + bijective XCD chunk (best
// measured FETCH).

#define STAGE_A(h) do { const unsigned short* g_ = A + gsA + (size_t)(h) * 32;               \
  __builtin_amdgcn_global_load_lds((const __attribute__((address_space(1))) void*)g_,        \
      (__attribute__((address_space(3))) void*)(&sA[(h) & 3][0] + tid * 8), 16, 0, 0);       \
  __builtin_amdgcn_global_load_lds((const __attribute__((address_space(1))) void*)(g_ + (size_t)128 * K), \
      (__attribute__((address_space(3))) void*)(&sA[(h) & 3][4096] + tid * 8), 16, 0, 0); } while (0)
#define STAGE_B(h) do { const unsigned short* g_ = B + gsB + (size_t)(h) * 32;               \
  __builtin_amdgcn_global_load_lds((const __attribute__((address_space(1))) void*)g_,        \
      (__attribute__((address_space(3))) void*)(&sB[(h) & 3][0] + tid * 8), 16, 0, 0);       \
  __builtin_amdgcn_global_load_lds((const __attribute__((address_space(1))) void*)(g_ + (size_t)128 * K), \
      (__attribute__((address_space(3))) void*)(&sB[(h) & 3][4096] + tid * 8), 16, 0, 0); } while (0)

#define LDA(s, m) (*(const bf16x8*)((const char*)&sA[s][0] + offA + (m) * 1024))
#define LDB(s, n) (*(const bf16x8*)((const char*)&sB[s][0] + offB + (n) * 1024))

template <int GELU>
__global__ __launch_bounds__(512, 2) void k_gemm256(const unsigned short* __restrict__ A,
                                                    const unsigned short* __restrict__ B,
                                                    void* __restrict__ C,
                                                    int M, int N, int K) {
  __shared__ __align__(16) unsigned short sA[4][8192];
  __shared__ __align__(16) unsigned short sB[4][8192];
  const int tid = threadIdx.x;
  const int lane = tid & 63;
  const int wave = tid >> 6;
  const int wm = wave >> 2, wn = wave & 3;
  const int r16 = lane & 15, q = lane >> 4;

  // Raster: bijective XCD chunk + grouped-m (GM=16, m-fastest within group).
  const int nbx = N >> 8;
  const int cpx = gridDim.x >> 3;
  const int g = (blockIdx.x & 7) * cpx + (blockIdx.x >> 3);
  const int gw = nbx << 4;                 // blocks per group (pow2 here)
  const int grp = g / gw;
  const int rem = g - grp * gw;
  const int m0 = (grp * 16 + (rem & 15)) * 256;
  const int n0 = (rem >> 4) * 256;

  const int rA = wm * 128 + r16;
  const int rB = wn * 64 + r16;
  const int offA = rA * 64 + ((q * 16) ^ (((rA >> 1) & 3) << 4));
  const int offB = rB * 64 + ((q * 16) ^ (((rB >> 1) & 3) << 4));

  const int sr = tid >> 2;                        // staging row (0..127)
  const int ssrc = (tid & 3) ^ ((sr >> 1) & 3);   // pre-swizzled global 16B slot
  const size_t gsA = (size_t)(m0 + sr) * K + (size_t)ssrc * 8;
  const size_t gsB = (size_t)(n0 + sr) * K + (size_t)ssrc * 8;

  f32x4 acc[8][4] = {};
  const int NT = K >> 6;

  // prologue: slabs 0,1,2 (A+B) = 12 instrs/wave; vmcnt(8) => slab 0 landed
  STAGE_A(0); STAGE_B(0); STAGE_A(1); STAGE_B(1); STAGE_A(2); STAGE_B(2);
  asm volatile("s_waitcnt vmcnt(8)" ::: "memory");
  __builtin_amdgcn_s_barrier();

  for (int t = 0; t < NT; ++t) {
    const int s0 = (2 * t) & 3, s1 = (2 * t + 1) & 3;
    const int h3 = 2 * t + 3, h4 = 2 * t + 4;
    bf16x8 af[4], bf[4];

    // ---- phase 1: kk0, m0-3 (8 ds_reads) ; stage A(2t+3)
#pragma unroll
    for (int i = 0; i < 4; ++i) af[i] = LDA(s0, i);
#pragma unroll
    for (int j = 0; j < 4; ++j) bf[j] = LDB(s0, j);
    if (h3 < 2 * NT) STAGE_A(h3);
    __builtin_amdgcn_s_barrier();
    __builtin_amdgcn_s_setprio(1);
#pragma unroll
    for (int i = 0; i < 4; ++i)
#pragma unroll
      for (int j = 0; j < 4; ++j)
        acc[i][j] = __builtin_amdgcn_mfma_f32_16x16x32_bf16(af[i], bf[j], acc[i][j], 0, 0, 0);
    __builtin_amdgcn_s_setprio(0);
    __builtin_amdgcn_s_barrier();

    // ---- phase 2: kk0, m4-7 (4 ds_reads, B reused) ; stage B(2t+3)
    //      end: counted vmcnt so slab s1 (read in p3/p4) is landed after bar
#pragma unroll
    for (int i = 0; i < 4; ++i) af[i] = LDA(s0, 4 + i);
    if (h3 < 2 * NT) STAGE_B(h3);
    __builtin_amdgcn_s_barrier();
    __builtin_amdgcn_s_setprio(1);
#pragma unroll
    for (int i = 0; i < 4; ++i)
#pragma unroll
      for (int j = 0; j < 4; ++j)
        acc[4 + i][j] = __builtin_amdgcn_mfma_f32_16x16x32_bf16(af[i], bf[j], acc[4 + i][j], 0, 0, 0);
    __builtin_amdgcn_s_setprio(0);
    if (t < NT - 1) { asm volatile("s_waitcnt vmcnt(8)" ::: "memory"); }
    else            { asm volatile("s_waitcnt vmcnt(0)" ::: "memory"); }
    __builtin_amdgcn_s_barrier();

    // ---- phase 3: kk1, m0-3 (8 ds_reads) ; stage A(2t+4)
#pragma unroll
    for (int i = 0; i < 4; ++i) af[i] = LDA(s1, i);
#pragma unroll
    for (int j = 0; j < 4; ++j) bf[j] = LDB(s1, j);
    if (h4 < 2 * NT) STAGE_A(h4);
    __builtin_amdgcn_s_barrier();
    __builtin_amdgcn_s_setprio(1);
#pragma unroll
    for (int i = 0; i < 4; ++i)
#pragma unroll
      for (int j = 0; j < 4; ++j)
        acc[i][j] = __builtin_amdgcn_mfma_f32_16x16x32_bf16(af[i], bf[j], acc[i][j], 0, 0, 0);
    __builtin_amdgcn_s_setprio(0);
    __builtin_amdgcn_s_barrier();

    // ---- phase 4: kk1, m4-7 (4 ds_reads) ; stage B(2t+4)
    //      end: counted vmcnt so slab s0' (next tile p1/p2) is landed
#pragma unroll
    for (int i = 0; i < 4; ++i) af[i] = LDA(s1, 4 + i);
    if (h4 < 2 * NT) STAGE_B(h4);
    __builtin_amdgcn_s_barrier();
    __builtin_amdgcn_s_setprio(1);
#pragma unroll
    for (int i = 0; i < 4; ++i)
#pragma unroll
      for (int j = 0; j < 4; ++j)
        acc[4 + i][j] = __builtin_amdgcn_mfma_f32_16x16x32_bf16(af[i], bf[j], acc[4 + i][j], 0, 0, 0);
    __builtin_amdgcn_s_setprio(0);
    if (t < NT - 2) { asm volatile("s_waitcnt vmcnt(8)" ::: "memory"); }
    else            { asm volatile("s_waitcnt vmcnt(4)" ::: "memory"); }
    __builtin_amdgcn_s_barrier();
  }

  // epilogue: C/D layout col=lane&15, row=(lane>>4)*4+reg
  const int mb = m0 + wm * 128 + q * 4;
  const int nb = n0 + wn * 64 + r16;
#pragma unroll
  for (int i = 0; i < 8; ++i) {
#pragma unroll
    for (int j = 0; j < 4; ++j) {
#pragma unroll
      for (int r = 0; r < 4; ++r) {
        int row = mb + i * 16 + r;
        int col = nb + j * 16;
        float v = acc[i][j][r];
        if (GELU) {
          v = 0.5f * v * (1.0f + erff(v * 0.70710678118654752440f));
          ((unsigned short*)C)[(size_t)row * N + col] = f2bf(v);
        } else {
          ((float*)C)[(size_t)row * N + col] = v;
        }
      }
    }
  }
}

extern "C" void kernel_launch(void* const* d_in, const int* in_sizes, int n_in,
                              void* d_out, int out_size, void* d_ws, size_t ws_size,
                              hipStream_t stream) {
  const float* x  = (const float*)d_in[0];
  const int* uqw  = (const int*)d_in[1];
  const int* uqz  = (const int*)d_in[2];
  const float* usc = (const float*)d_in[3];
  const int* dqw  = (const int*)d_in[4];
  const int* dqz  = (const int*)d_in[5];
  const float* dsc = (const float*)d_in[6];
  float* out = (float*)d_out;

  const int T = 8192, D = 4096, F = 16384;
  char* ws = (char*)d_ws;
  unsigned short* xb = (unsigned short*)ws;                                  // 64 MiB
  unsigned short* h  = (unsigned short*)(ws + (size_t)T * D * 2);            // 256 MiB
  unsigned short* wt = (unsigned short*)(ws + (size_t)T * D * 2 + (size_t)T * F * 2); // 128 MiB

  k_f32_to_bf16<<<dim3((T * D) / (256 * 8)), 256, 0, stream>>>(x, xb);
  k_dequant_t<<<dim3(D / 64, F / 64), 256, 0, stream>>>(uqw, uqz, usc, wt, D, F);
  k_gemm256<1><<<dim3((T / 256) * (F / 256)), 512, 0, stream>>>(xb, wt, (void*)h, T, F, D);
  k_dequant_t<<<dim3(F / 64, D / 64), 256, 0, stream>>>(dqw, dqz, dsc, wt, F, D);
  k_gemm256<0><<<dim3((T / 256) * (D / 256)), 512, 0, stream>>>(h, wt, (void*)out, T, D, F);
}

// Round 8
// 2342.371 us; speedup vs baseline: 1.4196x; 1.1266x over previous
//
#include <hip/hip_runtime.h>

typedef __attribute__((ext_vector_type(8))) __bf16 bf16x8;
typedef __attribute__((ext_vector_type(4))) float f32x4;

#define DEV __device__ __forceinline__

DEV unsigned short f2bf(float f) {
  unsigned int u = __float_as_uint(f);
  u += 0x7FFFu + ((u >> 16) & 1u);   // RNE
  return (unsigned short)(u >> 16);
}

// ---------------- kernel 1: f32 -> bf16 (vectorized) ----------------
__global__ __launch_bounds__(256) void k_f32_to_bf16(const float* __restrict__ x,
                                                     unsigned short* __restrict__ y) {
  size_t i = ((size_t)blockIdx.x * 256 + threadIdx.x) * 8;
  float4 a = *(const float4*)(x + i);
  float4 b = *(const float4*)(x + i + 4);
  union { unsigned short u[8]; uint4 v; } o;
  o.u[0] = f2bf(a.x); o.u[1] = f2bf(a.y); o.u[2] = f2bf(a.z); o.u[3] = f2bf(a.w);
  o.u[4] = f2bf(b.x); o.u[5] = f2bf(b.y); o.u[6] = f2bf(b.z); o.u[7] = f2bf(b.w);
  *(uint4*)(y + i) = o.v;
}

// ------- kernel 2: AWQ int4 dequant -> W^T bf16 [N][K] (LDS transpose) -------
__global__ __launch_bounds__(256) void k_dequant_t(const int* __restrict__ qw,
                                                   const int* __restrict__ qz,
                                                   const float* __restrict__ sc,
                                                   unsigned short* __restrict__ wt,
                                                   int K, int N) {
  __shared__ __align__(16) unsigned short st[64][72];
  const int k0 = blockIdx.x * 64, n0 = blockIdx.y * 64;
  const int t = threadIdx.x;
  const int g = k0 >> 7;
  const int Np = N >> 3;
#pragma unroll
  for (int it = 0; it < 2; ++it) {
    int idx = t + it * 256;
    int k = idx >> 3;
    int nc = idx & 7;
    unsigned int w = (unsigned int)qw[(size_t)(k0 + k) * Np + (n0 >> 3) + nc];
    unsigned int z = (unsigned int)qz[(size_t)g * Np + (n0 >> 3) + nc];
#pragma unroll
    for (int i = 0; i < 8; ++i) {
      float s = sc[(size_t)g * N + n0 + nc * 8 + i];
      float v = ((float)(int)((w >> (4 * i)) & 0xFu) -
                 (float)(int)((z >> (4 * i)) & 0xFu)) * s;
      st[nc * 8 + i][k] = f2bf(v);
    }
  }
  __syncthreads();
  const int n = t >> 2, c = t & 3;
  uint4 v0 = *(const uint4*)&st[n][c * 16];
  uint4 v1 = *(const uint4*)&st[n][c * 16 + 8];
  unsigned short* dst = wt + (size_t)(n0 + n) * K + k0 + c * 16;
  *(uint4*)dst = v0;
  *(uint4*)(dst + 8) = v1;
}

// ------- kernel 3: 256x256 GEMM, reg-dbuf pipeline  C = A[M][K] * B^T([N][K]) ---
// 512 threads = 8 waves (2M x 4N), per-wave out 128x64 (acc[8][4] of 16x16).
// LDS: A,B rings of 4 K-slabs (256 rows x 32 k bf16 = 16KB each) = 128 KiB.
// R7 post-mortem: the 8-phase 2-barrier-per-phase lockstep SERIALIZED ds_read
// and MFMA (per-tile: 2480 MFMA + ~2000 LDS + ~1500 barrier = 6500 cyc, 38%).
// New structure: per half-tile {vmcnt; barrier; 12 ds_reads of NEXT slab into
// the other reg set; STAGE slab+3; 32 MFMA on current reg set}. MFMA has no
// dep on the just-issued reads -> LDS drain hides under MFMA. 2 barriers/tile.
// Frags ping-pong in named regs (static indexing; rule #20).
// vmcnt ledger (4 VMEM instr/wave/half): steady vmcnt(4); e(NT-1) vmcnt(0);
// o(NT-1) skips sync (nothing left to land).

#define STAGE_A(h) do { const unsigned short* g_ = A + gsA + (size_t)(h) * 32;               \
  __builtin_amdgcn_global_load_lds((const __attribute__((address_space(1))) void*)g_,        \
      (__attribute__((address_space(3))) void*)(&sA[(h) & 3][0] + tid * 8), 16, 0, 0);       \
  __builtin_amdgcn_global_load_lds((const __attribute__((address_space(1))) void*)(g_ + (size_t)128 * K), \
      (__attribute__((address_space(3))) void*)(&sA[(h) & 3][4096] + tid * 8), 16, 0, 0); } while (0)
#define STAGE_B(h) do { const unsigned short* g_ = B + gsB + (size_t)(h) * 32;               \
  __builtin_amdgcn_global_load_lds((const __attribute__((address_space(1))) void*)g_,        \
      (__attribute__((address_space(3))) void*)(&sB[(h) & 3][0] + tid * 8), 16, 0, 0);       \
  __builtin_amdgcn_global_load_lds((const __attribute__((address_space(1))) void*)(g_ + (size_t)128 * K), \
      (__attribute__((address_space(3))) void*)(&sB[(h) & 3][4096] + tid * 8), 16, 0, 0); } while (0)

#define LDA(s, m) (*(const bf16x8*)((const char*)&sA[s][0] + offA + (m) * 1024))
#define LDB(s, n) (*(const bf16x8*)((const char*)&sB[s][0] + offB + (n) * 1024))

template <int GELU>
__global__ __launch_bounds__(512, 2) void k_gemm256(const unsigned short* __restrict__ A,
                                                    const unsigned short* __restrict__ B,
                                                    void* __restrict__ C,
                                                    int M, int N, int K) {
  __shared__ __align__(16) unsigned short sA[4][8192];
  __shared__ __align__(16) unsigned short sB[4][8192];
  const int tid = threadIdx.x;
  const int lane = tid & 63;
  const int wave = tid >> 6;
  const int wm = wave >> 2, wn = wave & 3;
  const int r16 = lane & 15, q = lane >> 4;

  // Raster: bijective XCD chunk + grouped-m (GM=16, m-fastest within group).
  const int nbx = N >> 8;
  const int cpx = gridDim.x >> 3;
  const int g = (blockIdx.x & 7) * cpx + (blockIdx.x >> 3);
  const int gw = nbx << 4;
  const int grp = g / gw;
  const int rem = g - grp * gw;
  const int m0 = (grp * 16 + (rem & 15)) * 256;
  const int n0 = (rem >> 4) * 256;

  const int rA = wm * 128 + r16;
  const int rB = wn * 64 + r16;
  const int offA = rA * 64 + ((q * 16) ^ (((rA >> 1) & 3) << 4));
  const int offB = rB * 64 + ((q * 16) ^ (((rB >> 1) & 3) << 4));

  const int sr = tid >> 2;                        // staging row (0..127)
  const int ssrc = (tid & 3) ^ ((sr >> 1) & 3);   // pre-swizzled global 16B slot
  const size_t gsA = (size_t)(m0 + sr) * K + (size_t)ssrc * 8;
  const size_t gsB = (size_t)(n0 + sr) * K + (size_t)ssrc * 8;

  f32x4 acc[8][4] = {};
  bf16x8 pA0[8], pB0[4], pA1[8], pB1[4];
  const int NT = K >> 6;

  // prologue: stage slabs 0,1,2; slab 0 landed; load its frags
  STAGE_A(0); STAGE_B(0); STAGE_A(1); STAGE_B(1); STAGE_A(2); STAGE_B(2);
  asm volatile("s_waitcnt vmcnt(8)" ::: "memory");
  __builtin_amdgcn_s_barrier();
#pragma unroll
  for (int i = 0; i < 8; ++i) pA0[i] = LDA(0, i);
#pragma unroll
  for (int j = 0; j < 4; ++j) pB0[j] = LDB(0, j);

  for (int t = 0; t < NT; ++t) {
    const int s1 = (2 * t + 1) & 3, s2 = (2 * t + 2) & 3;

    // ---- even half: MFMA slab 2t (p0) ; read 2t+1 -> p1 ; stage 2t+3
    if (t < NT - 1) { asm volatile("s_waitcnt vmcnt(4)" ::: "memory"); }
    else            { asm volatile("s_waitcnt vmcnt(0)" ::: "memory"); }
    __builtin_amdgcn_s_barrier();
#pragma unroll
    for (int i = 0; i < 8; ++i) pA1[i] = LDA(s1, i);
#pragma unroll
    for (int j = 0; j < 4; ++j) pB1[j] = LDB(s1, j);
    if (t < NT - 1) { STAGE_A(2 * t + 3); STAGE_B(2 * t + 3); }
    __builtin_amdgcn_s_setprio(1);
#pragma unroll
    for (int i = 0; i < 8; ++i)
#pragma unroll
      for (int j = 0; j < 4; ++j)
        acc[i][j] = __builtin_amdgcn_mfma_f32_16x16x32_bf16(pA0[i], pB0[j], acc[i][j], 0, 0, 0);
    __builtin_amdgcn_s_setprio(0);

    // ---- odd half: MFMA slab 2t+1 (p1) ; read 2t+2 -> p0 ; stage 2t+4
    if (t < NT - 1) {
      asm volatile("s_waitcnt vmcnt(4)" ::: "memory");
      __builtin_amdgcn_s_barrier();
#pragma unroll
      for (int i = 0; i < 8; ++i) pA0[i] = LDA(s2, i);
#pragma unroll
      for (int j = 0; j < 4; ++j) pB0[j] = LDB(s2, j);
      if (t < NT - 2) { STAGE_A(2 * t + 4); STAGE_B(2 * t + 4); }
    }
    __builtin_amdgcn_s_setprio(1);
#pragma unroll
    for (int i = 0; i < 8; ++i)
#pragma unroll
      for (int j = 0; j < 4; ++j)
        acc[i][j] = __builtin_amdgcn_mfma_f32_16x16x32_bf16(pA1[i], pB1[j], acc[i][j], 0, 0, 0);
    __builtin_amdgcn_s_setprio(0);
  }

  // epilogue: C/D layout col=lane&15, row=(lane>>4)*4+reg
  const int mb = m0 + wm * 128 + q * 4;
  const int nb = n0 + wn * 64 + r16;
#pragma unroll
  for (int i = 0; i < 8; ++i) {
#pragma unroll
    for (int j = 0; j < 4; ++j) {
#pragma unroll
      for (int r = 0; r < 4; ++r) {
        int row = mb + i * 16 + r;
        int col = nb + j * 16;
        float v = acc[i][j][r];
        if (GELU) {
          v = 0.5f * v * (1.0f + erff(v * 0.70710678118654752440f));
          ((unsigned short*)C)[(size_t)row * N + col] = f2bf(v);
        } else {
          ((float*)C)[(size_t)row * N + col] = v;
        }
      }
    }
  }
}

extern "C" void kernel_launch(void* const* d_in, const int* in_sizes, int n_in,
                              void* d_out, int out_size, void* d_ws, size_t ws_size,
                              hipStream_t stream) {
  const float* x  = (const float*)d_in[0];
  const int* uqw  = (const int*)d_in[1];
  const int* uqz  = (const int*)d_in[2];
  const float* usc = (const float*)d_in[3];
  const int* dqw  = (const int*)d_in[4];
  const int* dqz  = (const int*)d_in[5];
  const float* dsc = (const float*)d_in[6];
  float* out = (float*)d_out;

  const int T = 8192, D = 4096, F = 16384;
  char* ws = (char*)d_ws;
  unsigned short* xb = (unsigned short*)ws;                                  // 64 MiB
  unsigned short* h  = (unsigned short*)(ws + (size_t)T * D * 2);            // 256 MiB
  unsigned short* wt = (unsigned short*)(ws + (size_t)T * D * 2 + (size_t)T * F * 2); // 128 MiB

  k_f32_to_bf16<<<dim3((T * D) / (256 * 8)), 256, 0, stream>>>(x, xb);
  k_dequant_t<<<dim3(D / 64, F / 64), 256, 0, stream>>>(uqw, uqz, usc, wt, D, F);
  k_gemm256<1><<<dim3((T / 256) * (F / 256)), 512, 0, stream>>>(xb, wt, (void*)h, T, F, D);
  k_dequant_t<<<dim3(F / 64, D / 64), 256, 0, stream>>>(dqw, dqz, dsc, wt, F, D);
  k_gemm256<0><<<dim3((T / 256) * (D / 256)), 512, 0, stream>>>(h, wt, (void*)out, T, D, F);
}